// Round 3
// baseline (291.970 us; speedup 1.0000x reference)
//
#include <hip/hip_runtime.h>
#include <math.h>

#define KTOP 16
#define B1   512     // pass-1 blocks (== T2, pass2 adopts one block's list per thread)
#define T1   512     // pass-1 threads per block
#define T2   512     // pass-2 threads

typedef unsigned long long ull;

// Sortable key: larger distance first, ties -> smaller index first.
// d >= 0 so its float bits are monotone in value.
__device__ __forceinline__ ull pack_key(float d, unsigned idx) {
    return ((ull)__float_as_uint(d) << 32) | (ull)(0xFFFFFFFFu - idx);
}

// Sorted-descending bubble insert, constant indices only (SROA-safe).
__device__ __forceinline__ void insert_key(ull (&k)[KTOP], ull key) {
    ull t = key;
#pragma unroll
    for (int j = 0; j < KTOP; ++j) {
        const ull a = k[j];
        const bool c = (t > a);
        k[j] = c ? t : a;
        t    = c ? a : t;
    }
}

__device__ __forceinline__ float dist3(float x, float y, float z,
                                       float px, float py, float pz) {
#pragma clang fp contract(off)
    const float dx = x - px;
    const float dy = y - py;
    const float dz = z - pz;
    const float s  = (dx * dx + dy * dy) + dz * dz;
    return sqrtf(s);
}

// 4 waves/EU minimum -> VGPR cap 128 -> 16 waves/CU resident for MLP.
__global__ __launch_bounds__(T1, 4) void pass1_topk(const float* __restrict__ P,
                                                    const int*   __restrict__ ipq,
                                                    int n,
                                                    ull* __restrict__ cand) {
    const int tid    = threadIdx.x;
    const int gid    = blockIdx.x * T1 + tid;
    const int stride = B1 * T1;

    const int i0 = ipq[0];
    const float pix = P[6 * i0 + 0];
    const float piy = P[6 * i0 + 1];
    const float piz = P[6 * i0 + 2];

    ull k[KTOP];
#pragma unroll
    for (int j = 0; j < KTOP; ++j) k[j] = 0ull;

    const float4* __restrict__ P4 = (const float4*)P;
    const int nQuad = n >> 2;   // 4 points = 6 float4 = 96 B per quad-group

    for (int q = gid; q < nQuad; q += stride) {
        // Issue all 6 loads up front: 6 dwordx4 in flight per wave.
        const float4 r0 = P4[6 * q + 0];
        const float4 r1 = P4[6 * q + 1];
        const float4 r2 = P4[6 * q + 2];
        const float4 r3 = P4[6 * q + 3];
        const float4 r4 = P4[6 * q + 4];
        const float4 r5 = P4[6 * q + 5];
        // points 4q..4q+3: (r0.xyz), (r1.z,r1.w,r2.x), (r3.xyz), (r4.z,r4.w,r5.x)
        const float d0 = dist3(r0.x, r0.y, r0.z, pix, piy, piz);
        const float d1 = dist3(r1.z, r1.w, r2.x, pix, piy, piz);
        const float d2 = dist3(r3.x, r3.y, r3.z, pix, piy, piz);
        const float d3 = dist3(r4.z, r4.w, r5.x, pix, piy, piz);
        const ull k0 = pack_key(d0, (unsigned)(4 * q + 0));
        const ull k1 = pack_key(d1, (unsigned)(4 * q + 1));
        const ull k2 = pack_key(d2, (unsigned)(4 * q + 2));
        const ull k3 = pack_key(d3, (unsigned)(4 * q + 3));
        if (k0 > k[KTOP - 1]) insert_key(k, k0);
        if (k1 > k[KTOP - 1]) insert_key(k, k1);
        if (k2 > k[KTOP - 1]) insert_key(k, k2);
        if (k3 > k[KTOP - 1]) insert_key(k, k3);
    }
    // Tail (n not divisible by 4)
    for (int p = (nQuad << 2) + gid; p < n; p += stride) {
        const float d = dist3(P[6 * p], P[6 * p + 1], P[6 * p + 2], pix, piy, piz);
        const ull key = pack_key(d, (unsigned)p);
        if (key > k[KTOP - 1]) insert_key(k, key);
    }

    // Block pop-max: 16 rounds, emit block top-16 sorted descending.
    __shared__ ull s_w[T1 / 64];
    __shared__ ull s_best;
    const int lane = tid & 63;
    const int wid  = tid >> 6;

    for (int r = 0; r < KTOP; ++r) {
        const ull mk = k[0];
        ull rv = mk;
#pragma unroll
        for (int m = 32; m >= 1; m >>= 1) {
            const ull ov = __shfl_xor(rv, m);
            if (ov > rv) rv = ov;
        }
        if (lane == 0) s_w[wid] = rv;
        __syncthreads();
        if (tid == 0) {
            ull b = s_w[0];
            for (int w = 1; w < T1 / 64; ++w) if (s_w[w] > b) b = s_w[w];
            s_best = b;
            cand[blockIdx.x * KTOP + r] = b;
        }
        __syncthreads();
        if (mk == s_best) {   // unique keys -> exactly one owner
#pragma unroll
            for (int j = 0; j < KTOP - 1; ++j) k[j] = k[j + 1];
            k[KTOP - 1] = 0ull;
        }
    }
}

// Thread t adopts pass-1 block t's sorted 16 keys in registers; 16 rounds of
// block pop-max; 16-thread epilogue.
__global__ __launch_bounds__(T2, 1) void pass2_final(const float* __restrict__ P,
                                                     const int*   __restrict__ ipq,
                                                     const float* __restrict__ W,
                                                     const float* __restrict__ bvec,
                                                     const ull*   __restrict__ cand,
                                                     float* __restrict__ out) {
    __shared__ ull s_w[T2 / 64];
    __shared__ ull s_best;
    __shared__ ull s_final[KTOP];

    const int tid  = threadIdx.x;
    const int lane = tid & 63;
    const int wid  = tid >> 6;

    ull k[KTOP];
    const ull* __restrict__ my = cand + (size_t)tid * KTOP;
#pragma unroll
    for (int j = 0; j < KTOP; ++j) k[j] = my[j];   // already sorted descending

    for (int r = 0; r < KTOP; ++r) {
        const ull mk = k[0];
        ull rv = mk;
#pragma unroll
        for (int m = 32; m >= 1; m >>= 1) {
            const ull ov = __shfl_xor(rv, m);
            if (ov > rv) rv = ov;
        }
        if (lane == 0) s_w[wid] = rv;
        __syncthreads();
        if (tid == 0) {
            ull b = s_w[0];
            for (int w = 1; w < T2 / 64; ++w) if (s_w[w] > b) b = s_w[w];
            s_best = b;
            s_final[r] = b;
        }
        __syncthreads();
        if (mk == s_best) {
#pragma unroll
            for (int j = 0; j < KTOP - 1; ++j) k[j] = k[j + 1];
            k[KTOP - 1] = 0ull;
        }
    }
    __syncthreads();

    // Epilogue: 16 threads build feat, apply W,b, write [nloc | R].
    if (tid < KTOP) {
        const ull kk = s_final[tid];
        const float d = __uint_as_float((unsigned)(kk >> 32));
        const unsigned idx = 0xFFFFFFFFu - (unsigned)(kk & 0xFFFFFFFFull);
        const int   i0  = ipq[0];
        const float pix = P[6 * i0 + 0], piy = P[6 * i0 + 1], piz = P[6 * i0 + 2];
        const float nx  = P[6 * (size_t)idx + 0];
        const float ny  = P[6 * (size_t)idx + 1];
        const float nz  = P[6 * (size_t)idx + 2];
        float dx, dy, dz;
        {
#pragma clang fp contract(off)
            dx = pix - nx; dy = piy - ny; dz = piz - nz;
        }
        const float feat[10] = { pix, piy, piz, nx, ny, nz, dx, dy, dz, d };
        float R[3];
#pragma unroll
        for (int r = 0; r < 3; ++r) {
            float acc = bvec[r];
#pragma unroll
            for (int c = 0; c < 10; ++c) acc += feat[c] * W[r * 10 + c];
            R[r] = acc;
        }
        out[6 * tid + 0] = nx;   out[6 * tid + 1] = ny;   out[6 * tid + 2] = nz;
        out[6 * tid + 3] = R[0]; out[6 * tid + 4] = R[1]; out[6 * tid + 5] = R[2];
    }
}

extern "C" void kernel_launch(void* const* d_in, const int* in_sizes, int n_in,
                              void* d_out, int out_size, void* d_ws, size_t ws_size,
                              hipStream_t stream) {
    const float* P    = (const float*)d_in[0];
    const float* W    = (const float*)d_in[1];
    const float* bvec = (const float*)d_in[2];
    const int*   ipq  = (const int*)d_in[3];
    float*       out  = (float*)d_out;

    const int n = in_sizes[0] / 6;
    ull* cand = (ull*)d_ws;

    pass1_topk<<<B1, T1, 0, stream>>>(P, ipq, n, cand);
    pass2_final<<<1, T2, 0, stream>>>(P, ipq, W, bvec, cand, out);
}